// Round 17
// baseline (132.375 us; speedup 1.0000x reference)
//
#include <hip/hip_runtime.h>
#include <math.h>

#define Nn 64
#define Tt 200
#define Bb 64

__device__ __forceinline__ float sigm(float x){ return 1.0f/(1.0f+__expf(-x)); }
__device__ __forceinline__ float tanh_fast(float x){
  x = fminf(fmaxf(x, -15.f), 15.f);
  float e = __expf(-2.f*x);
  return (1.f - e)/(1.f + e);
}

typedef __attribute__((ext_vector_type(2))) _Float16 h2v;
typedef __attribute__((ext_vector_type(4))) float f4;

#if __has_builtin(__builtin_amdgcn_fdot2)
#define DOT2(w,hv,acc) __builtin_amdgcn_fdot2((w),(hv),(acc),false)
#else
#define DOT2(w,hv,acc) fmaf((float)(w)[0],(float)(hv)[0], fmaf((float)(w)[1],(float)(hv)[1],(acc)))
#endif

__device__ __forceinline__ float h2f(ushort u){
  return (float)__builtin_bit_cast(_Float16, u);
}

// ---------------------------------------------------------------------------
// K1: build graph operators. L = -S_cheb, L2 = 2*S@S - I, G = S_gcn (+diag).
// ---------------------------------------------------------------------------
__global__ __launch_bounds__(1024) void k1_graphs(
    const int* __restrict__ sp_ei, const float* __restrict__ sp_ew,
    const int* __restrict__ fn_ei, const float* __restrict__ fn_ew,
    float* __restrict__ Lg, float* __restrict__ L2g, float* __restrict__ Gm)
{
  __shared__ float deg[Nn];
  __shared__ float dinv[Nn];
  __shared__ float S[64*68];            // padded stride 68
  const int tid = threadIdx.x;

  // ---- ChebConv operator (512 edges) ----
  if (tid < Nn) deg[tid] = 0.f;
  for (int i=tid;i<64*68;i+=1024) S[i]=0.f;
  __syncthreads();
  if (tid < 512) atomicAdd(&deg[sp_ei[tid]], sp_ew[tid]);   // deg over row
  __syncthreads();
  if (tid < Nn) dinv[tid] = (deg[tid] > 0.f) ? rsqrtf(deg[tid]) : 0.f;
  __syncthreads();
  if (tid < 512) {
    int r = sp_ei[tid], c = sp_ei[512+tid];
    atomicAdd(&S[c*68 + r], dinv[r]*sp_ew[tid]*dinv[c]);
  }
  __syncthreads();
  for (int i=tid;i<4096;i+=1024) Lg[i] = -S[(i>>6)*68 + (i&63)];   // Ltil = -S
  {
    const int n = tid>>4, mb = (tid&15)*4;
    float a0=0.f,a1=0.f,a2=0.f,a3=0.f;
    for (int j=0;j<64;j++){
      float snj = S[n*68+j];
      float4 v = *(const float4*)&S[j*68+mb];
      a0=fmaf(snj,v.x,a0); a1=fmaf(snj,v.y,a1);
      a2=fmaf(snj,v.z,a2); a3=fmaf(snj,v.w,a3);
    }
    L2g[n*64+mb+0] = 2.f*a0 - (n==mb+0 ? 1.f : 0.f);
    L2g[n*64+mb+1] = 2.f*a1 - (n==mb+1 ? 1.f : 0.f);
    L2g[n*64+mb+2] = 2.f*a2 - (n==mb+2 ? 1.f : 0.f);
    L2g[n*64+mb+3] = 2.f*a3 - (n==mb+3 ? 1.f : 0.f);
  }
  __syncthreads();   // all reads of S done before reuse

  // ---- GCNConv operator (1024 edges) ----
  if (tid < Nn) deg[tid] = 0.f;
  for (int i=tid;i<64*68;i+=1024) S[i]=0.f;
  __syncthreads();
  atomicAdd(&deg[fn_ei[1024+tid]], fn_ew[tid]);             // deg over col
  __syncthreads();
  if (tid < Nn) dinv[tid] = rsqrtf(deg[tid] + 1.f);
  __syncthreads();
  {
    int r = fn_ei[tid], c = fn_ei[1024+tid];
    atomicAdd(&S[c*68 + r], dinv[r]*fn_ew[tid]*dinv[c]);
  }
  __syncthreads();
  if (tid < Nn) S[tid*68 + tid] += dinv[tid]*dinv[tid];     // + diag(1/deg)
  __syncthreads();
  for (int i=tid;i<4096;i+=1024) Gm[i] = S[(i>>6)*68 + (i&63)];
}

// ---------------------------------------------------------------------------
// K2: fold Wih (+Wcheb/Wgcn/graph ops) into Aeff[384][64] and constv[384].
// ---------------------------------------------------------------------------
__global__ __launch_bounds__(64) void k2_aeff(
    const float* __restrict__ Wih_f, const float* __restrict__ bih_f,
    const float* __restrict__ Wih_b, const float* __restrict__ bih_b,
    const float* __restrict__ Wcheb, const float* __restrict__ bcheb,
    const float* __restrict__ Wgcn,  const float* __restrict__ bgcn,
    const float* __restrict__ Lg, const float* __restrict__ L2g,
    const float* __restrict__ Gm,
    float* __restrict__ Aeff, float* __restrict__ constv)
{
  const int g = blockIdx.x;                 // 0..383
  const int dir = (g >= 192) ? 1 : 0;
  const int grow = dir ? g - 192 : g;
  const float* Wih = dir ? Wih_b : Wih_f;
  const float* bih = dir ? bih_b : bih_f;

  __shared__ float wrow[64*129];
  __shared__ float arow[256];
  const int tid = threadIdx.x;              // 64 threads = 1 wave

  const float4* W4 = (const float4*)(Wih + (size_t)grow*8192);
  for (int i4 = tid; i4 < 2048; i4 += 64) {
    float4 v = W4[i4];
    int base = i4*4, row = base>>7, col = base&127;
    float* dst = &wrow[row*129+col];
    dst[0]=v.x; dst[1]=v.y; dst[2]=v.z; dst[3]=v.w;
  }
  __syncthreads();

  const int n = tid;
  float a0=0.f,a1=0.f,a2=0.f,a3=0.f,cp=0.f;
  for (int c=0;c<64;c++) {
    float w1 = wrow[n*129 + c];
    a0 = fmaf(w1, Wcheb[c],     a0);
    a1 = fmaf(w1, Wcheb[64+c],  a1);
    a2 = fmaf(w1, Wcheb[128+c], a2);
    cp = fmaf(w1, bcheb[c],     cp);
    float w2 = wrow[n*129 + 64 + c];
    a3 = fmaf(w2, Wgcn[c], a3);
    cp = fmaf(w2, bgcn[c], cp);
  }
  arow[n*4+0]=a0; arow[n*4+1]=a1; arow[n*4+2]=a2; arow[n*4+3]=a3;
  for (int off=32; off; off>>=1) cp += __shfl_down(cp, off, 64);
  if (tid==0) constv[g] = cp + bih[grow];
  __syncthreads();

  const int m = tid;
  float ae = arow[m*4+0];
  for (int nn2=0; nn2<64; nn2++) {
    ae = fmaf(arow[nn2*4+1], Lg [nn2*64+m], ae);
    ae = fmaf(arow[nn2*4+2], L2g[nn2*64+m], ae);
    ae = fmaf(arow[nn2*4+3], Gm [nn2*64+m], ae);
  }
  Aeff[g*64+m] = ae;
}

// ---------------------------------------------------------------------------
// K4: xp[12800][384](fp16) = X[12800][64] @ Aeff[384][64]^T + constv;
// x transpose fused into staging; 128x64 tiles (600 blocks); fp16 output
// halves the write traffic and k5's fetch.
// ---------------------------------------------------------------------------
__global__ __launch_bounds__(256) void k4_gemm(
    const float* __restrict__ x, const float* __restrict__ Aeff,
    const float* __restrict__ constv, _Float16* __restrict__ xp)
{
  const int m0 = blockIdx.x*128, g0 = blockIdx.y*64;
  __shared__ float sX[64*132];  // [k][row 0..127], stride 132
  __shared__ float sA[64*68];   // [k][g-row]
  const int tid = threadIdx.x;

  // ---- stage X tile with fused transpose ----
  {
    const int row = tid & 127;           // lane = row (t-direction)
    const int kq  = tid >> 7;            // 0..1
    const int m = m0 + row;
    const int b = m / 200;
    const int t = m - b*200;
    const float* xb = x + (size_t)b*64*200 + t;
    #pragma unroll
    for (int kk=0; kk<32; ++kk) {
      int k = kq*32 + kk;
      sX[k*132 + row] = xb[(size_t)k*200];
    }
  }
  // ---- stage Aeff tile (float4 loads) ----
  {
    const float4* A4 = (const float4*)Aeff;
    #pragma unroll
    for (int i=0;i<4;i++) {
      int f = tid + i*256;
      int r2 = f >> 4, kq2 = f & 15;
      float4 w = A4[(g0+r2)*16 + kq2];
      sA[(kq2*4+0)*68 + r2] = w.x;
      sA[(kq2*4+1)*68 + r2] = w.y;
      sA[(kq2*4+2)*68 + r2] = w.z;
      sA[(kq2*4+3)*68 + r2] = w.w;
    }
  }
  __syncthreads();

  const int tm = tid & 15, tn = tid >> 4;   // rows tm*8.., cols tn*4..
  float acc[8][4] = {};
  #pragma unroll 4
  for (int k=0;k<64;k++) {
    const float* xr = &sX[k*132 + tm*8];
    float4 a0 = *(const float4*)xr;
    float4 a1 = *(const float4*)(xr+4);
    float4 bb = *(const float4*)&sA[k*68 + tn*4];
    float av[8]={a0.x,a0.y,a0.z,a0.w,a1.x,a1.y,a1.z,a1.w};
    float bv[4]={bb.x,bb.y,bb.z,bb.w};
    #pragma unroll
    for (int i=0;i<8;i++)
      #pragma unroll
      for (int j=0;j<4;j++)
        acc[i][j] = fmaf(av[i], bv[j], acc[i][j]);
  }

  float cv[4];
  #pragma unroll
  for (int j=0;j<4;j++) cv[j] = constv[g0 + tn*4 + j];
  #pragma unroll
  for (int i=0;i<8;i++) {
    int mrow = m0 + tm*8 + i;
    union { ushort u[4]; uint2 v; } pk;
    #pragma unroll
    for (int j=0;j<4;j++)
      pk.u[j] = __builtin_bit_cast(ushort, (_Float16)(acc[i][j] + cv[j]));
    *(uint2*)&xp[(size_t)mrow*384 + g0 + tn*4] = pk.v;
  }
}

// ---------------------------------------------------------------------------
// K5: biGRU recurrence — R11/R16 structure (validated floor: ~84us, VGPR 132).
// Single wave per (b,dir); lane g owns hidden unit g. h broadcast via LDS
// (ds_write_b16 + 8x broadcast ds_read_b128). Weights resident as fp16 pairs;
// waves_per_eu(1,1) is the only config the allocator keeps them resident for.
// xp is fp16: prefetch keeps RAW USHORT in registers, converts at use (no
// cvt-after-load stall). gru_out stored fp16 for k6.
// ---------------------------------------------------------------------------
__global__ __launch_bounds__(64)
__attribute__((amdgpu_waves_per_eu(1, 1)))
void k5_gru(
    const _Float16* __restrict__ xp,
    const float* __restrict__ Whh_f, const float* __restrict__ bhh_f,
    const float* __restrict__ Whh_b, const float* __restrict__ bhh_b,
    _Float16* __restrict__ gru_out)
{
  const int bd = blockIdx.x;
  const int b = bd >> 1, dir = bd & 1;
  const int g = threadIdx.x & 63;
  const float* Whh = dir ? Whh_b : Whh_f;
  const float* bhh = dir ? bhh_b : bhh_f;

  h2v wr[32], wz[32], wn[32];
  #pragma unroll
  for (int i=0;i<32;i++){
    float2 a = ((const float2*)(Whh + (size_t)g*64))[i];
    float2 bq= ((const float2*)(Whh + (size_t)(64+g)*64))[i];
    float2 c = ((const float2*)(Whh + (size_t)(128+g)*64))[i];
    wr[i] = h2v{(_Float16)a.x, (_Float16)a.y};
    wz[i] = h2v{(_Float16)bq.x,(_Float16)bq.y};
    wn[i] = h2v{(_Float16)c.x, (_Float16)c.y};
  }
  const float br_ = bhh[g], bz_ = bhh[64+g], bn_ = bhh[128+g];

  __shared__ __align__(16) _Float16 hsh[64];   // packed fp16 h vector (128 B)
  hsh[g] = (_Float16)0.f;                      // initial h = 0

  const int t0 = dir ? (Tt-1) : 0;
  const int tstep = dir ? -1 : 1;
  const ushort* xb = (const ushort*)xp + (size_t)(b*Tt)*384 + dir*192 + g;
  _Float16* gout = gru_out + (size_t)(b*Tt)*128 + dir*64 + g;

  float h = 0.f;
  ushort xrA = xb[(size_t)t0*384], xzA = xb[(size_t)t0*384+64], xnA = xb[(size_t)t0*384+128];
  const int t1 = t0 + tstep;
  ushort xrB = xb[(size_t)t1*384], xzB = xb[(size_t)t1*384+64], xnB = xb[(size_t)t1*384+128];

  int t = t0;
  auto STEP = [&](ushort& xr, ushort& xz, ushort& xn){
    // broadcast-read the full packed h vector: 8x ds_read_b128, conflict-free
    h2v hv[32];
    {
      const uint4* hp4 = (const uint4*)hsh;
      #pragma unroll
      for (int q=0;q<8;q++){
        union { uint4 v; h2v p[4]; } uu;
        uu.v = hp4[q];
        hv[q*4+0]=uu.p[0]; hv[q*4+1]=uu.p[1]; hv[q*4+2]=uu.p[2]; hv[q*4+3]=uu.p[3];
      }
    }

    const float cxr = h2f(xr), cxz = h2f(xz), cxn = h2f(xn);
    const int tpre = t + 2*tstep;
    if ((unsigned)tpre < (unsigned)Tt) {   // depth-2 prefetch, reload after use
      xr = xb[(size_t)tpre*384];
      xz = xb[(size_t)tpre*384+64];
      xn = xb[(size_t)tpre*384+128];
    }

    float ar0=0.f,ar1=0.f,az0=0.f,az1=0.f,an0=0.f,an1=0.f;
    #pragma unroll
    for (int i=0;i<32;i+=2){
      ar0 = DOT2(wr[i],  hv[i],  ar0);  az0 = DOT2(wz[i],  hv[i],  az0);  an0 = DOT2(wn[i],  hv[i],  an0);
      ar1 = DOT2(wr[i+1],hv[i+1],ar1);  az1 = DOT2(wz[i+1],hv[i+1],az1);  an1 = DOT2(wn[i+1],hv[i+1],an1);
    }

    float r   = sigm(cxr + (ar0+ar1) + br_);
    float z   = sigm(cxz + (az0+az1) + bz_);
    float nn2 = tanh_fast(cxn + r*((an0+an1) + bn_));
    float hnew = (1.f - z)*nn2 + z*h;
    h = hnew;
    _Float16 hf = (_Float16)hnew;
    hsh[g] = hf;                           // ds_write_b16 for next step
    gout[(size_t)t*128] = hf;
    t += tstep;
  };

  for (int sp=0; sp<Tt; sp+=2) { STEP(xrA,xzA,xnA); STEP(xrB,xzB,xnB); }
}

// ---------------------------------------------------------------------------
// K6: attention pooling + classifier. One block per batch item; 4 waves.
// gru_out is fp16 (half the read bytes, read twice).
// ---------------------------------------------------------------------------
__global__ __launch_bounds__(256) void k6_attn(
    const _Float16* __restrict__ gru_out,
    const float* __restrict__ attn_W, const float* __restrict__ attn_b,
    const float* __restrict__ clf_W,  const float* __restrict__ clf_b,
    float* __restrict__ out)
{
  const int b = blockIdx.x, tid = threadIdx.x;
  const int wv = tid >> 6, ln = tid & 63;
  __shared__ float aW[128], cW[128];
  __shared__ float s_s[Tt];
  __shared__ float wred[4];
  __shared__ float part[2][128];
  if (tid < 128) { aW[tid]=attn_W[tid]; cW[tid]=clf_W[tid]; }
  __syncthreads();

  float sc = -1e30f;
  if (tid < Tt) {
    const _Float16* row = gru_out + (size_t)(b*Tt + tid)*128;
    float acc = 0.f;
    for (int j=0;j<128;j++) acc = fmaf((float)row[j], aW[j], acc);
    sc = tanhf(acc + attn_b[0]);
    s_s[tid] = sc;
  }
  float m = sc;
  #pragma unroll
  for (int off=32; off; off>>=1) m = fmaxf(m, __shfl_xor(m, off, 64));
  if (ln==0) wred[wv] = m;
  __syncthreads();
  const float mx = fmaxf(fmaxf(wred[0],wred[1]), fmaxf(wred[2],wred[3]));

  float e = 0.f;
  if (tid < Tt) { e = __expf(sc - mx); s_s[tid] = e; }
  float s = e;
  #pragma unroll
  for (int off=32; off; off>>=1) s += __shfl_xor(s, off, 64);
  __syncthreads();
  if (ln==0) wred[wv] = s;
  __syncthreads();
  const float total = wred[0]+wred[1]+wred[2]+wred[3];

  const int j = tid & 127, half = tid >> 7;
  float c = 0.f;
  const _Float16* gb = gru_out + (size_t)(b*Tt)*128 + j;
  for (int t = half*100; t < half*100 + 100; ++t)
    c = fmaf(s_s[t], (float)gb[(size_t)t*128], c);
  part[half][j] = c;
  __syncthreads();

  float p = 0.f;
  if (tid < 128) p = ((part[0][j] + part[1][j]) / total) * cW[j];
  #pragma unroll
  for (int off=32; off; off>>=1) p += __shfl_xor(p, off, 64);
  __syncthreads();
  if (ln==0) wred[wv] = p;
  __syncthreads();
  if (tid==0) out[b] = sigm(wred[0] + wred[1] + clf_b[0]);
}

// ---------------------------------------------------------------------------
extern "C" void kernel_launch(void* const* d_in, const int* in_sizes, int n_in,
                              void* d_out, int out_size, void* d_ws, size_t ws_size,
                              hipStream_t stream)
{
  const float* x      = (const float*)d_in[0];
  const int*   sp_ei  = (const int*)  d_in[1];
  const float* sp_ew  = (const float*)d_in[2];
  const int*   fn_ei  = (const int*)  d_in[3];
  const float* fn_ew  = (const float*)d_in[4];
  const float* Wcheb  = (const float*)d_in[5];
  const float* bcheb  = (const float*)d_in[6];
  const float* Wgcn   = (const float*)d_in[7];
  const float* bgcn   = (const float*)d_in[8];
  const float* Wih_f  = (const float*)d_in[9];
  const float* Whh_f  = (const float*)d_in[10];
  const float* bih_f  = (const float*)d_in[11];
  const float* bhh_f  = (const float*)d_in[12];
  const float* Wih_b  = (const float*)d_in[13];
  const float* Whh_b  = (const float*)d_in[14];
  const float* bih_b  = (const float*)d_in[15];
  const float* bhh_b  = (const float*)d_in[16];
  const float* attn_W = (const float*)d_in[17];
  const float* attn_b = (const float*)d_in[18];
  const float* clf_W  = (const float*)d_in[19];
  const float* clf_b  = (const float*)d_in[20];
  float* out = (float*)d_out;

  float* ws     = (float*)d_ws;
  float* Lg     = ws;                    // 4096
  float* L2g    = Lg   + 4096;           // 4096
  float* Gm     = L2g  + 4096;           // 4096
  float* Aeff   = Gm   + 4096;           // 384*64 = 24576
  float* constv = Aeff + 24576;          // 384 (+pad to 512)
  _Float16* xp  = (_Float16*)(constv + 512);       // 12800*384 fp16 = 2457600 floats
  _Float16* gro = (_Float16*)(constv + 512 + 2457600);  // 12800*128 fp16

  hipLaunchKernelGGL(k1_graphs,    dim3(1),      dim3(1024), 0, stream,
                     sp_ei, sp_ew, fn_ei, fn_ew, Lg, L2g, Gm);
  hipLaunchKernelGGL(k2_aeff,      dim3(384),    dim3(64),   0, stream,
                     Wih_f, bih_f, Wih_b, bih_b, Wcheb, bcheb, Wgcn, bgcn,
                     Lg, L2g, Gm, Aeff, constv);
  hipLaunchKernelGGL(k4_gemm,      dim3(100, 6), dim3(256),  0, stream,
                     x, Aeff, constv, xp);
  hipLaunchKernelGGL(k5_gru,       dim3(128),    dim3(64),   0, stream,
                     xp, Whh_f, bhh_f, Whh_b, bhh_b, gro);
  hipLaunchKernelGGL(k6_attn,      dim3(64),     dim3(256),  0, stream,
                     gro, attn_W, attn_b, clf_W, clf_b, out);
}

// Round 19
// 132.206 us; speedup vs baseline: 1.0013x; 1.0013x over previous
//
#include <hip/hip_runtime.h>
#include <math.h>

#define Nn 64
#define Tt 200
#define Bb 64

__device__ __forceinline__ float sigm(float x){ return 1.0f/(1.0f+__expf(-x)); }
__device__ __forceinline__ float tanh_fast(float x){
  x = fminf(fmaxf(x, -15.f), 15.f);
  float e = __expf(-2.f*x);
  return (1.f - e)/(1.f + e);
}

typedef __attribute__((ext_vector_type(2))) _Float16 h2v;
typedef __attribute__((ext_vector_type(4))) float f4;

// fp16 dot2 with fp32 accumulate (v_dot2_f32_f16).
#if __has_builtin(__builtin_amdgcn_fdot2)
#define DOT2(w,hv,acc) __builtin_amdgcn_fdot2((w),(hv),(acc),false)
#else
#define DOT2(w,hv,acc) fmaf((float)(w)[0],(float)(hv)[0], fmaf((float)(w)[1],(float)(hv)[1],(acc)))
#endif

// ---------------------------------------------------------------------------
// K1: build graph operators. L = -S_cheb, L2 = 2*S@S - I, G = S_gcn (+diag).
// ---------------------------------------------------------------------------
__global__ __launch_bounds__(1024) void k1_graphs(
    const int* __restrict__ sp_ei, const float* __restrict__ sp_ew,
    const int* __restrict__ fn_ei, const float* __restrict__ fn_ew,
    float* __restrict__ Lg, float* __restrict__ L2g, float* __restrict__ Gm)
{
  __shared__ float deg[Nn];
  __shared__ float dinv[Nn];
  __shared__ float S[64*68];            // padded stride 68
  const int tid = threadIdx.x;

  // ---- ChebConv operator (512 edges) ----
  if (tid < Nn) deg[tid] = 0.f;
  for (int i=tid;i<64*68;i+=1024) S[i]=0.f;
  __syncthreads();
  if (tid < 512) atomicAdd(&deg[sp_ei[tid]], sp_ew[tid]);   // deg over row
  __syncthreads();
  if (tid < Nn) dinv[tid] = (deg[tid] > 0.f) ? rsqrtf(deg[tid]) : 0.f;
  __syncthreads();
  if (tid < 512) {
    int r = sp_ei[tid], c = sp_ei[512+tid];
    atomicAdd(&S[c*68 + r], dinv[r]*sp_ew[tid]*dinv[c]);
  }
  __syncthreads();
  for (int i=tid;i<4096;i+=1024) Lg[i] = -S[(i>>6)*68 + (i&63)];   // Ltil = -S
  {
    const int n = tid>>4, mb = (tid&15)*4;
    float a0=0.f,a1=0.f,a2=0.f,a3=0.f;
    for (int j=0;j<64;j++){
      float snj = S[n*68+j];
      float4 v = *(const float4*)&S[j*68+mb];
      a0=fmaf(snj,v.x,a0); a1=fmaf(snj,v.y,a1);
      a2=fmaf(snj,v.z,a2); a3=fmaf(snj,v.w,a3);
    }
    L2g[n*64+mb+0] = 2.f*a0 - (n==mb+0 ? 1.f : 0.f);
    L2g[n*64+mb+1] = 2.f*a1 - (n==mb+1 ? 1.f : 0.f);
    L2g[n*64+mb+2] = 2.f*a2 - (n==mb+2 ? 1.f : 0.f);
    L2g[n*64+mb+3] = 2.f*a3 - (n==mb+3 ? 1.f : 0.f);
  }
  __syncthreads();   // all reads of S done before reuse

  // ---- GCNConv operator (1024 edges) ----
  if (tid < Nn) deg[tid] = 0.f;
  for (int i=tid;i<64*68;i+=1024) S[i]=0.f;
  __syncthreads();
  atomicAdd(&deg[fn_ei[1024+tid]], fn_ew[tid]);             // deg over col
  __syncthreads();
  if (tid < Nn) dinv[tid] = rsqrtf(deg[tid] + 1.f);
  __syncthreads();
  {
    int r = fn_ei[tid], c = fn_ei[1024+tid];
    atomicAdd(&S[c*68 + r], dinv[r]*fn_ew[tid]*dinv[c]);
  }
  __syncthreads();
  if (tid < Nn) S[tid*68 + tid] += dinv[tid]*dinv[tid];     // + diag(1/deg)
  __syncthreads();
  for (int i=tid;i<4096;i+=1024) Gm[i] = S[(i>>6)*68 + (i&63)];
}

// ---------------------------------------------------------------------------
// K2: fold Wih (+Wcheb/Wgcn/graph ops) into Aeff[384][64] and constv[384].
// ---------------------------------------------------------------------------
__global__ __launch_bounds__(64) void k2_aeff(
    const float* __restrict__ Wih_f, const float* __restrict__ bih_f,
    const float* __restrict__ Wih_b, const float* __restrict__ bih_b,
    const float* __restrict__ Wcheb, const float* __restrict__ bcheb,
    const float* __restrict__ Wgcn,  const float* __restrict__ bgcn,
    const float* __restrict__ Lg, const float* __restrict__ L2g,
    const float* __restrict__ Gm,
    float* __restrict__ Aeff, float* __restrict__ constv)
{
  const int g = blockIdx.x;                 // 0..383
  const int dir = (g >= 192) ? 1 : 0;
  const int grow = dir ? g - 192 : g;
  const float* Wih = dir ? Wih_b : Wih_f;
  const float* bih = dir ? bih_b : bih_f;

  __shared__ float wrow[64*129];
  __shared__ float arow[256];
  const int tid = threadIdx.x;              // 64 threads = 1 wave

  const float4* W4 = (const float4*)(Wih + (size_t)grow*8192);
  for (int i4 = tid; i4 < 2048; i4 += 64) {
    float4 v = W4[i4];
    int base = i4*4, row = base>>7, col = base&127;
    float* dst = &wrow[row*129+col];
    dst[0]=v.x; dst[1]=v.y; dst[2]=v.z; dst[3]=v.w;
  }
  __syncthreads();

  const int n = tid;
  float a0=0.f,a1=0.f,a2=0.f,a3=0.f,cp=0.f;
  for (int c=0;c<64;c++) {
    float w1 = wrow[n*129 + c];
    a0 = fmaf(w1, Wcheb[c],     a0);
    a1 = fmaf(w1, Wcheb[64+c],  a1);
    a2 = fmaf(w1, Wcheb[128+c], a2);
    cp = fmaf(w1, bcheb[c],     cp);
    float w2 = wrow[n*129 + 64 + c];
    a3 = fmaf(w2, Wgcn[c], a3);
    cp = fmaf(w2, bgcn[c], cp);
  }
  arow[n*4+0]=a0; arow[n*4+1]=a1; arow[n*4+2]=a2; arow[n*4+3]=a3;
  for (int off=32; off; off>>=1) cp += __shfl_down(cp, off, 64);
  if (tid==0) constv[g] = cp + bih[grow];
  __syncthreads();

  const int m = tid;
  float ae = arow[m*4+0];
  for (int nn2=0; nn2<64; nn2++) {
    ae = fmaf(arow[nn2*4+1], Lg [nn2*64+m], ae);
    ae = fmaf(arow[nn2*4+2], L2g[nn2*64+m], ae);
    ae = fmaf(arow[nn2*4+3], Gm [nn2*64+m], ae);
  }
  Aeff[g*64+m] = ae;
}

// ---------------------------------------------------------------------------
// K4: xp[12800][384] = X[12800][64] @ Aeff[384][64]^T + constv, with the
// x transpose fused into staging (k3 eliminated).
// ---------------------------------------------------------------------------
__global__ __launch_bounds__(256) void k4_gemm(
    const float* __restrict__ x, const float* __restrict__ Aeff,
    const float* __restrict__ constv, float* __restrict__ xp)
{
  const int m0 = blockIdx.x*64, g0 = blockIdx.y*64;
  __shared__ float sX[64*68];   // [k][m-row], stride 68
  __shared__ float sA[64*68];   // [k][g-row]
  const int tid = threadIdx.x;

  // ---- stage X tile with fused transpose ----
  {
    const int row = tid & 63;            // lane = row (t-direction)
    const int kq  = tid >> 6;            // 0..3
    const int m = m0 + row;
    const int b = m / 200;
    const int t = m - b*200;
    const float* xb = x + (size_t)b*64*200 + t;
    #pragma unroll
    for (int kk=0; kk<16; ++kk) {
      int k = kq*16 + kk;
      sX[k*68 + row] = xb[(size_t)k*200];
    }
  }
  // ---- stage Aeff tile (float4 loads) ----
  {
    const float4* A4 = (const float4*)Aeff;
    #pragma unroll
    for (int i=0;i<4;i++) {
      int f = tid + i*256;
      int r2 = f >> 4, kq2 = f & 15;
      float4 w = A4[(g0+r2)*16 + kq2];
      sA[(kq2*4+0)*68 + r2] = w.x;
      sA[(kq2*4+1)*68 + r2] = w.y;
      sA[(kq2*4+2)*68 + r2] = w.z;
      sA[(kq2*4+3)*68 + r2] = w.w;
    }
  }
  __syncthreads();

  const int tm = tid & 15, tn = tid >> 4;
  float acc[4][4] = {};
  #pragma unroll 8
  for (int k=0;k<64;k++) {
    float4 a  = *(const float4*)&sX[k*68 + tm*4];
    float4 bb = *(const float4*)&sA[k*68 + tn*4];
    float av[4]={a.x,a.y,a.z,a.w}, bv[4]={bb.x,bb.y,bb.z,bb.w};
    #pragma unroll
    for (int i=0;i<4;i++)
      #pragma unroll
      for (int j=0;j<4;j++)
        acc[i][j] = fmaf(av[i], bv[j], acc[i][j]);
  }

  float cv[4];
  #pragma unroll
  for (int j=0;j<4;j++) cv[j] = constv[g0 + tn*4 + j];
  #pragma unroll
  for (int i=0;i<4;i++) {
    int mrow = m0 + tm*4 + i;
    #pragma unroll
    for (int j=0;j<4;j++)
      xp[mrow*384 + g0 + tn*4 + j] = acc[i][j] + cv[j];
  }
}

// ---------------------------------------------------------------------------
// K5: biGRU recurrence — validated floor (~84us, VGPR 132). Single wave per
// (b,dir); lane g owns hidden unit g. h broadcast via LDS (ds_write_b16 +
// 8x broadcast ds_read_b128). Weights resident as fp16 pairs (96 regs);
// waves_per_eu(1,1) is the only config the allocator keeps them resident for
// (R13/R14/R15 all remat'd and lost >=2x). Latency-bound: 200 serial steps x
// ~1000cyc chain (LDS roundtrip + 96-inst dot issue + serial gate chain).
// ---------------------------------------------------------------------------
__global__ __launch_bounds__(64)
__attribute__((amdgpu_waves_per_eu(1, 1)))
void k5_gru(
    const float* __restrict__ xp,
    const float* __restrict__ Whh_f, const float* __restrict__ bhh_f,
    const float* __restrict__ Whh_b, const float* __restrict__ bhh_b,
    float* __restrict__ gru_out)
{
  const int bd = blockIdx.x;
  const int b = bd >> 1, dir = bd & 1;
  const int g = threadIdx.x & 63;
  const float* Whh = dir ? Whh_b : Whh_f;
  const float* bhh = dir ? bhh_b : bhh_f;

  // resident fp16-packed weight rows (3 gate rows for this lane's unit)
  h2v wr[32], wz[32], wn[32];
  #pragma unroll
  for (int i=0;i<32;i++){
    float2 a = ((const float2*)(Whh + (size_t)g*64))[i];
    float2 bq= ((const float2*)(Whh + (size_t)(64+g)*64))[i];
    float2 c = ((const float2*)(Whh + (size_t)(128+g)*64))[i];
    wr[i] = h2v{(_Float16)a.x, (_Float16)a.y};
    wz[i] = h2v{(_Float16)bq.x,(_Float16)bq.y};
    wn[i] = h2v{(_Float16)c.x, (_Float16)c.y};
  }
  const float br_ = bhh[g], bz_ = bhh[64+g], bn_ = bhh[128+g];

  __shared__ __align__(16) _Float16 hsh[64];   // packed fp16 h vector (128 B)
  hsh[g] = (_Float16)0.f;                      // initial h = 0

  const int t0 = dir ? (Tt-1) : 0;
  const int tstep = dir ? -1 : 1;
  const float* xb = xp + (size_t)(b*Tt)*384 + dir*192 + g;
  float* gout = gru_out + (size_t)(b*Tt)*128 + dir*64 + g;

  float h = 0.f;
  float xrA = xb[(size_t)t0*384], xzA = xb[(size_t)t0*384+64], xnA = xb[(size_t)t0*384+128];
  const int t1 = t0 + tstep;
  float xrB = xb[(size_t)t1*384], xzB = xb[(size_t)t1*384+64], xnB = xb[(size_t)t1*384+128];

  int t = t0;
  auto STEP = [&](float& xr, float& xz, float& xn){
    // broadcast-read the full packed h vector: 8x ds_read_b128, conflict-free
    h2v hv[32];
    {
      const uint4* hp4 = (const uint4*)hsh;
      #pragma unroll
      for (int q=0;q<8;q++){
        union { uint4 v; h2v p[4]; } uu;
        uu.v = hp4[q];
        hv[q*4+0]=uu.p[0]; hv[q*4+1]=uu.p[1]; hv[q*4+2]=uu.p[2]; hv[q*4+3]=uu.p[3];
      }
    }

    const float cxr = xr, cxz = xz, cxn = xn;
    const int tpre = t + 2*tstep;
    if ((unsigned)tpre < (unsigned)Tt) {   // depth-2 prefetch, reload after use
      xr = xb[(size_t)tpre*384];
      xz = xb[(size_t)tpre*384+64];
      xn = xb[(size_t)tpre*384+128];
    }

    float ar0=0.f,ar1=0.f,az0=0.f,az1=0.f,an0=0.f,an1=0.f;
    #pragma unroll
    for (int i=0;i<32;i+=2){
      ar0 = DOT2(wr[i],  hv[i],  ar0);  az0 = DOT2(wz[i],  hv[i],  az0);  an0 = DOT2(wn[i],  hv[i],  an0);
      ar1 = DOT2(wr[i+1],hv[i+1],ar1);  az1 = DOT2(wz[i+1],hv[i+1],az1);  an1 = DOT2(wn[i+1],hv[i+1],an1);
    }

    float r   = sigm(cxr + (ar0+ar1) + br_);
    float z   = sigm(cxz + (az0+az1) + bz_);
    float nn2 = tanh_fast(cxn + r*((an0+an1) + bn_));
    float hnew = (1.f - z)*nn2 + z*h;
    h = hnew;
    hsh[g] = (_Float16)hnew;               // ds_write_b16 for next step
    gout[(size_t)t*128] = hnew;
    t += tstep;
  };

  for (int sp=0; sp<Tt; sp+=2) { STEP(xrA,xzA,xnA); STEP(xrB,xzB,xnB); }
}

// ---------------------------------------------------------------------------
// K6: attention pooling + classifier. One block per batch item; 4 waves.
// Barrier-lean: wave-level shfl_xor reductions, ctx loop split across halves.
// ---------------------------------------------------------------------------
__global__ __launch_bounds__(256) void k6_attn(
    const float* __restrict__ gru_out,
    const float* __restrict__ attn_W, const float* __restrict__ attn_b,
    const float* __restrict__ clf_W,  const float* __restrict__ clf_b,
    float* __restrict__ out)
{
  const int b = blockIdx.x, tid = threadIdx.x;
  const int wv = tid >> 6, ln = tid & 63;
  __shared__ float aW[128], cW[128];
  __shared__ float s_s[Tt];
  __shared__ float wred[4];
  __shared__ float part[2][128];
  if (tid < 128) { aW[tid]=attn_W[tid]; cW[tid]=clf_W[tid]; }
  __syncthreads();

  float sc = -1e30f;
  if (tid < Tt) {
    const float* row = gru_out + (size_t)(b*Tt + tid)*128;
    float acc = 0.f;
    for (int j=0;j<128;j++) acc = fmaf(row[j], aW[j], acc);
    sc = tanhf(acc + attn_b[0]);
    s_s[tid] = sc;
  }
  float m = sc;
  #pragma unroll
  for (int off=32; off; off>>=1) m = fmaxf(m, __shfl_xor(m, off, 64));
  if (ln==0) wred[wv] = m;
  __syncthreads();
  const float mx = fmaxf(fmaxf(wred[0],wred[1]), fmaxf(wred[2],wred[3]));

  float e = 0.f;
  if (tid < Tt) { e = __expf(sc - mx); s_s[tid] = e; }
  float s = e;
  #pragma unroll
  for (int off=32; off; off>>=1) s += __shfl_xor(s, off, 64);
  __syncthreads();
  if (ln==0) wred[wv] = s;
  __syncthreads();
  const float total = wred[0]+wred[1]+wred[2]+wred[3];

  const int j = tid & 127, half = tid >> 7;
  float c = 0.f;
  const float* gb = gru_out + (size_t)(b*Tt)*128 + j;
  for (int t = half*100; t < half*100 + 100; ++t)
    c = fmaf(s_s[t], gb[(size_t)t*128], c);
  part[half][j] = c;
  __syncthreads();

  float p = 0.f;
  if (tid < 128) p = ((part[0][j] + part[1][j]) / total) * cW[j];
  #pragma unroll
  for (int off=32; off; off>>=1) p += __shfl_xor(p, off, 64);
  __syncthreads();
  if (ln==0) wred[wv] = p;
  __syncthreads();
  if (tid==0) out[b] = sigm(wred[0] + wred[1] + clf_b[0]);
}

// ---------------------------------------------------------------------------
extern "C" void kernel_launch(void* const* d_in, const int* in_sizes, int n_in,
                              void* d_out, int out_size, void* d_ws, size_t ws_size,
                              hipStream_t stream)
{
  const float* x      = (const float*)d_in[0];
  const int*   sp_ei  = (const int*)  d_in[1];
  const float* sp_ew  = (const float*)d_in[2];
  const int*   fn_ei  = (const int*)  d_in[3];
  const float* fn_ew  = (const float*)d_in[4];
  const float* Wcheb  = (const float*)d_in[5];
  const float* bcheb  = (const float*)d_in[6];
  const float* Wgcn   = (const float*)d_in[7];
  const float* bgcn   = (const float*)d_in[8];
  const float* Wih_f  = (const float*)d_in[9];
  const float* Whh_f  = (const float*)d_in[10];
  const float* bih_f  = (const float*)d_in[11];
  const float* bhh_f  = (const float*)d_in[12];
  const float* Wih_b  = (const float*)d_in[13];
  const float* Whh_b  = (const float*)d_in[14];
  const float* bih_b  = (const float*)d_in[15];
  const float* bhh_b  = (const float*)d_in[16];
  const float* attn_W = (const float*)d_in[17];
  const float* attn_b = (const float*)d_in[18];
  const float* clf_W  = (const float*)d_in[19];
  const float* clf_b  = (const float*)d_in[20];
  float* out = (float*)d_out;

  float* ws     = (float*)d_ws;
  float* Lg     = ws;                    // 4096
  float* L2g    = Lg   + 4096;           // 4096
  float* Gm     = L2g  + 4096;           // 4096
  float* Aeff   = Gm   + 4096;           // 384*64 = 24576
  float* constv = Aeff + 24576;          // 384 (+pad to 512)
  float* xp     = constv + 512;          // 12800*384 = 4915200
  float* gro    = xp   + 4915200;        // 12800*128 = 1638400

  hipLaunchKernelGGL(k1_graphs,    dim3(1),      dim3(1024), 0, stream,
                     sp_ei, sp_ew, fn_ei, fn_ew, Lg, L2g, Gm);
  hipLaunchKernelGGL(k2_aeff,      dim3(384),    dim3(64),   0, stream,
                     Wih_f, bih_f, Wih_b, bih_b, Wcheb, bcheb, Wgcn, bgcn,
                     Lg, L2g, Gm, Aeff, constv);
  hipLaunchKernelGGL(k4_gemm,      dim3(200, 6), dim3(256),  0, stream,
                     x, Aeff, constv, xp);
  hipLaunchKernelGGL(k5_gru,       dim3(128),    dim3(64),   0, stream,
                     xp, Whh_f, bhh_f, Whh_b, bhh_b, gro);
  hipLaunchKernelGGL(k6_attn,      dim3(64),     dim3(256),  0, stream,
                     gro, attn_W, attn_b, clf_W, clf_b, out);
}